// Round 9
// baseline (249.847 us; speedup 1.0000x reference)
//
#include <hip/hip_runtime.h>

// TTN Conv: out[n,p,o,site] = sum_{c,i,j,k,l} a_i b_j c_k d_l * W[c,p,site,ijkl,o] + bias
// Per site: GEMM D[n=128][po=48] = sum_k A[n][k=768] * W[k][po], bf16 MFMA 16x16x32.
//
// x:       (128, 3, 4, 32, 32) fp32
// tensors: (3, 8, 31, 31, 256, 6) fp32  -> per (c,p,site): [m=256][o=6] contiguous
// bias:    (8, 31, 31, 6) fp32
// out:     (128, 8, 6, 31, 31) fp32 = out[f*961 + site], f = n*48 + p*6 + o
//
// R11 = R8 components (ALL HW-proven clean: VGPR 64, WRITE 23.6 MB) with ONE
// variable changed: CODE SIZE. The flat fully-unrolled 12-chunk loop (~12-14 KB
// body vs 32 KB L1I shared per CU-quad) becomes outer c-loop (#pragma unroll 1)
// x inner 4-mb unrolled body (~3-4 KB hot code).
// Why: 6 falsified theories (vmcnt drain R7, DRAM stride R8, convoy R9,
// prefetch depth, scratch, x-divergence R10) all neutral at conv=85us with
// VALUBusy pinned at exactly 14% even when VALU work changed 30% (R10) --
// issue-limited, not execution-limited. First-dispatch runs 2-2.5x slower
// (cold code). This probes instruction-supply as the pacer.
// No cross-c prefetch: x+W panel loaded at c-top (~900cyc exposed x3 per
// block, amortized across 2-4 co-resident blocks/CU) -- keeps probe clean.
//
// Phase 1 (1 block/site, 256 thr): K in 3 c-panels x 4 chunks of 64.
//   sA[128][64] bf16 (str 72), sW[48][64] bf16 (str 72), fused lgkm-only
//   barriers (R7-proven). Wave w: n in [w*32,+32), 2x3 MFMA tiles.
// Phase 2: tiled transpose ws(961 x 6144) -> out(6144 x 961) + bias.
// Canaries: WRITE ~23.6 MB, VGPR <= 128, LDS 25600 B, FETCH ~95-100 MB.

typedef __attribute__((ext_vector_type(8))) short short8;
typedef __attribute__((ext_vector_type(4))) float floatx4;
typedef __attribute__((ext_vector_type(4))) unsigned int uintx4;

#define WS_ELEMS (961u * 6144u)
#define SA_STR 72
#define SW_STR 72

static __device__ __forceinline__ unsigned short f2bf(float f) {
  union { float f; unsigned u; } v; v.f = f;
  unsigned r = v.u + 0x7FFFu + ((v.u >> 16) & 1u);   // RNE to bf16
  return (unsigned short)(r >> 16);
}

// lgkm drain + workgroup barrier as ONE volatile asm with memory clobber
// (R7-proven): no memory op crosses it; vmcnt untouched.
static __device__ __forceinline__ void barrier_lgkm() {
  asm volatile("s_waitcnt lgkmcnt(0)\n\ts_barrier" ::: "memory");
  __builtin_amdgcn_sched_barrier(0);
}

template <bool TO_WS>
__global__ __launch_bounds__(256, 4)
void ttn_conv_mfma(const float* __restrict__ x,
                   const float* __restrict__ tensors,
                   const float* __restrict__ bias,
                   float* __restrict__ dst) {
  __shared__ __align__(16) unsigned short sA[128 * SA_STR];  // 18432 B
  __shared__ __align__(16) unsigned short sW[48 * SW_STR];   //  6912 B

  const int site = blockIdx.x;
  const int xx = site / 31, yy = site - xx * 31;
  const int t = threadIdx.x;
  const int lane = t & 63, wave = t >> 6;
  const int row = lane & 15, quad = lane >> 4;

  const int n_st = t & 127;   // sA staging: this thread's n
  const int h = t >> 7;       // sA staging: ij4 in {2h, 2h+1}  (j = 2h+e, i = mb)
  const int p_st = t >> 5;    // sW staging: p (0..7)
  const int q_st = t & 31;    // sW staging: m-pair index (m = 2q, 2q+1)

  floatx4 acc[2][3];
#pragma unroll
  for (int i0 = 0; i0 < 2; ++i0)
#pragma unroll
    for (int j0 = 0; j0 < 3; ++j0)
      acc[i0][j0] = (floatx4){0.f, 0.f, 0.f, 0.f};

  float areg[4], b0, b1, cdreg[16];
  float4 wv[12];  // full c-panel W slice; constant-indexed (mb unroll-const)

  const float* xpb = x + (size_t)n_st * 3 * 4096 + xx * 32 + yy;
  const float* wsite = tensors + ((size_t)(p_st * 961 + site)) * 1536 + 12 * q_st;

#pragma unroll 1
  for (int c = 0; c < 3; ++c) {
    // ---- x factors for this c (scalar loads; 4B-aligned only) ----
    {
      const float* xp = xpb + (size_t)c * 4096;
      float bq[4], cq[4], dq[4];
#pragma unroll
      for (int i = 0; i < 4; ++i) {
        const float* r0 = xp + i * 1024;
        areg[i] = r0[0];   // a_i = x[n,c,i,xx,  yy  ]
        cq[i]   = r0[1];   // c_i = x[n,c,i,xx,  yy+1]
        bq[i]   = r0[32];  // b_i = x[n,c,i,xx+1,yy  ]
        dq[i]   = r0[33];  // d_i = x[n,c,i,xx+1,yy+1]
      }
      b0 = h ? bq[2] : bq[0];
      b1 = h ? bq[3] : bq[1];
#pragma unroll
      for (int k2 = 0; k2 < 4; ++k2)
#pragma unroll
        for (int l2 = 0; l2 < 4; ++l2)
          cdreg[k2 * 4 + l2] = cq[k2] * dq[l2];
    }
    // ---- W panel for this c: 4 x 48B at 1536B stride (R8 pattern, proven) ----
    {
      const float* src = wsite + (size_t)c * (8u * 961u * 1536u);
#pragma unroll
      for (int mb2 = 0; mb2 < 4; ++mb2) {
        wv[3 * mb2 + 0] = *(const float4*)(src + mb2 * 384);
        wv[3 * mb2 + 1] = *(const float4*)(src + mb2 * 384 + 4);
        wv[3 * mb2 + 2] = *(const float4*)(src + mb2 * 384 + 8);
      }
    }

#pragma unroll
    for (int mb = 0; mb < 4; ++mb) {
      barrier_lgkm();  // prev chunk's frag reads (lgkm) done before overwrite

      // ---- stage sW[po][m_local] (R8's explicit pairs, proven clean) ----
      {
        const float4 w0 = wv[3 * mb + 0];
        const float4 w1 = wv[3 * mb + 1];
        const float4 w2 = wv[3 * mb + 2];
        unsigned short* dW = &sW[(p_st * 6) * SW_STR + 2 * q_st];
        // W[2q][o] = w[o], W[2q+1][o] = w[6+o] (12 contiguous floats)
        *(unsigned*)&dW[0 * SW_STR] = (unsigned)f2bf(w0.x) | ((unsigned)f2bf(w1.z) << 16);
        *(unsigned*)&dW[1 * SW_STR] = (unsigned)f2bf(w0.y) | ((unsigned)f2bf(w1.w) << 16);
        *(unsigned*)&dW[2 * SW_STR] = (unsigned)f2bf(w0.z) | ((unsigned)f2bf(w2.x) << 16);
        *(unsigned*)&dW[3 * SW_STR] = (unsigned)f2bf(w0.w) | ((unsigned)f2bf(w2.y) << 16);
        *(unsigned*)&dW[4 * SW_STR] = (unsigned)f2bf(w1.x) | ((unsigned)f2bf(w2.z) << 16);
        *(unsigned*)&dW[5 * SW_STR] = (unsigned)f2bf(w1.y) | ((unsigned)f2bf(w2.w) << 16);
      }
      // ---- stage sA[n][ij4*16+kl] = (a_mb * b_{2h+e}) * cd[kl] ----
#pragma unroll
      for (int e = 0; e < 2; ++e) {
        const float ab = areg[mb] * (e ? b1 : b0);
        unsigned pk[8];
#pragma unroll
        for (int u = 0; u < 8; ++u)
          pk[u] = (unsigned)f2bf(ab * cdreg[2 * u]) |
                  ((unsigned)f2bf(ab * cdreg[2 * u + 1]) << 16);
        uintx4* dp = (uintx4*)&sA[n_st * SA_STR + (2 * h + e) * 16];
        uintx4 v0 = {pk[0], pk[1], pk[2], pk[3]};
        uintx4 v1 = {pk[4], pk[5], pk[6], pk[7]};
        dp[0] = v0;
        dp[1] = v1;
      }
      barrier_lgkm();  // ds_writes visible before frag reads; vmcnt NOT drained

      // ---- MFMA: 2 K-steps of 32, wave tile 2(M) x 3(N) ----
#pragma unroll
      for (int ks = 0; ks < 2; ++ks) {
        const int kof = ks * 32 + quad * 8;
        short8 af[2], bf[3];
#pragma unroll
        for (int mt = 0; mt < 2; ++mt)
          af[mt] = *(const short8*)&sA[(wave * 32 + mt * 16 + row) * SA_STR + kof];
#pragma unroll
        for (int nt = 0; nt < 3; ++nt)
          bf[nt] = *(const short8*)&sW[(nt * 16 + row) * SW_STR + kof];
#pragma unroll
        for (int mt = 0; mt < 2; ++mt)
#pragma unroll
          for (int nt = 0; nt < 3; ++nt)
            acc[mt][nt] = __builtin_amdgcn_mfma_f32_16x16x32_bf16(
                af[mt], bf[nt], acc[mt][nt], 0, 0, 0);
      }
    }
  }

  // ---- epilogue: D row = quad*4+r (n-local), col = lane&15 (po-local) ----
  if (TO_WS) {
#pragma unroll
    for (int mt = 0; mt < 2; ++mt)
#pragma unroll
      for (int r = 0; r < 4; ++r) {
        const int n = wave * 32 + mt * 16 + quad * 4 + r;
#pragma unroll
        for (int nt = 0; nt < 3; ++nt) {
          const int po = nt * 16 + row;
          dst[(size_t)site * 6144 + n * 48 + po] = acc[mt][nt][r];
        }
      }
  } else {
#pragma unroll
    for (int mt = 0; mt < 2; ++mt)
#pragma unroll
      for (int r = 0; r < 4; ++r) {
        const int n = wave * 32 + mt * 16 + quad * 4 + r;
#pragma unroll
        for (int nt = 0; nt < 3; ++nt) {
          const int po = nt * 16 + row;
          const int p = po / 6, o = po - p * 6;
          dst[(size_t)(n * 48 + po) * 961 + site] =
              acc[mt][nt][r] + bias[(p * 961 + site) * 6 + o];
        }
      }
  }
}

// out[f*961 + site] = ws[site*6144 + f] + bias[(p*961+site)*6 + o],  f = n*48+p*6+o
__global__ __launch_bounds__(256, 8)
void ttn_transpose_bias(const float* __restrict__ ws,
                        const float* __restrict__ bias,
                        float* __restrict__ out) {
  __shared__ float tile[32][33];
  const int f0 = blockIdx.x * 32;
  const int s0 = blockIdx.y * 32;
  const int tx = threadIdx.x;       // 0..31
  const int ty = threadIdx.y;       // 0..7

#pragma unroll
  for (int rr = 0; rr < 4; ++rr) {
    const int srow = ty + rr * 8;
    const int site = s0 + srow;
    if (site < 961)
      tile[srow][tx] = ws[(size_t)site * 6144 + f0 + tx];
  }
  __syncthreads();

#pragma unroll
  for (int rr = 0; rr < 4; ++rr) {
    const int fy = ty + rr * 8;
    const int f = f0 + fy;
    const int site = s0 + tx;
    if (site < 961) {
      const int po = f % 48;
      const int p = po / 6, o = po - p * 6;
      out[(size_t)f * 961 + site] = tile[tx][fy] + bias[(p * 961 + site) * 6 + o];
    }
  }
}

extern "C" void kernel_launch(void* const* d_in, const int* in_sizes, int n_in,
                              void* d_out, int out_size, void* d_ws, size_t ws_size,
                              hipStream_t stream) {
  const float* x       = (const float*)d_in[0];
  const float* tensors = (const float*)d_in[1];
  const float* bias    = (const float*)d_in[2];
  float* out           = (float*)d_out;

  const size_t need = (size_t)WS_ELEMS * sizeof(float);
  if (d_ws != nullptr && ws_size >= need) {
    float* ws = (float*)d_ws;
    hipLaunchKernelGGL((ttn_conv_mfma<true>), dim3(961), dim3(256), 0, stream,
                       x, tensors, bias, ws);
    hipLaunchKernelGGL(ttn_transpose_bias, dim3(192, 31), dim3(32, 8), 0, stream,
                       ws, bias, out);
  } else {
    hipLaunchKernelGGL((ttn_conv_mfma<false>), dim3(961), dim3(256), 0, stream,
                       x, tensors, bias, out);
  }
}